// Round 9
// baseline (340.760 us; speedup 1.0000x reference)
//
#include <hip/hip_runtime.h>
#include <hip/hip_bf16.h>
#include <math.h>

#define DIMD 1024
#define LSEQ 2048
#define BATCH 4
#define NHEAD 8
#define HD 128
#define NROWS (BATCH*LSEQ)   // 8192
#define PROJC (5*DIMD)       // 5120
#define BRC (2*DIMD)         // 2048

typedef __attribute__((ext_vector_type(8))) short short8;
typedef __attribute__((ext_vector_type(4))) short short4v;
typedef __attribute__((ext_vector_type(4))) float floatx4;

__device__ __forceinline__ float bf2f(short s) {
  unsigned int u = ((unsigned int)(unsigned short)s) << 16;
  return __builtin_bit_cast(float, u);
}
__device__ __forceinline__ short f2bf(float f) {
  unsigned int u = __builtin_bit_cast(unsigned int, f);
  unsigned int lsb = (u >> 16) & 1u;
  u += 0x7fffu + lsb;
  return (short)(u >> 16);
}

// global->LDS direct DMA, 16B per lane. LDS dest is wave-uniform base;
// HW scatters lane i to lds + i*16.
__device__ __forceinline__ void gl2lds16(const short* g, short* l) {
  __builtin_amdgcn_global_load_lds(
      (const __attribute__((address_space(1))) unsigned int*)(unsigned long long)g,
      (__attribute__((address_space(3))) unsigned int*)(unsigned int)(unsigned long long)l,
      16, 0, 0);
}

__device__ __forceinline__ void wgbar() {
  asm volatile("" ::: "memory");
  __builtin_amdgcn_s_barrier();
  asm volatile("" ::: "memory");
}

// ------- fused weight-convert (fp32->bf16) + LayerNorm (x -> h bf16) -------
__global__ __launch_bounds__(256) void pre_kernel(
    const float* __restrict__ x, const float* __restrict__ gamma,
    const float* __restrict__ beta, short* __restrict__ h,
    const float* __restrict__ s1, short* __restrict__ d1, int n1_4,
    const float* __restrict__ s2, short* __restrict__ d2, int n2_4,
    int nblk_cvt) {
  int bid = blockIdx.x;
  if (bid < nblk_cvt) {
    int i = bid * 256 + threadIdx.x;
    const float* src; short* dst;
    if (i < n1_4) { src = s1; dst = d1; }
    else { i -= n1_4; if (i >= n2_4) return; src = s2; dst = d2; }
    float4 v = *(const float4*)(src + (size_t)i * 4);
    short4v o;
    o[0] = f2bf(v.x); o[1] = f2bf(v.y); o[2] = f2bf(v.z); o[3] = f2bf(v.w);
    *(short4v*)(dst + (size_t)i * 4) = o;
    return;
  }
  int row = bid - nblk_cvt;
  int c = threadIdx.x * 4;
  const float* xr = x + (size_t)row * DIMD;
  float4 v = *(const float4*)(xr + c);
  float f[4] = {v.x, v.y, v.z, v.w};
  float sum = 0.f, sq = 0.f;
  for (int i = 0; i < 4; ++i) { sum += f[i]; sq += f[i]*f[i]; }
  for (int off = 1; off < 64; off <<= 1) {
    sum += __shfl_xor(sum, off);
    sq  += __shfl_xor(sq, off);
  }
  __shared__ float red[8];
  int wid = threadIdx.x >> 6;
  if ((threadIdx.x & 63) == 0) { red[wid*2] = sum; red[wid*2+1] = sq; }
  __syncthreads();
  sum = red[0]+red[2]+red[4]+red[6];
  sq  = red[1]+red[3]+red[5]+red[7];
  float mu = sum * (1.0f/DIMD);
  float var = sq * (1.0f/DIMD) - mu*mu;
  float rstd = rsqrtf(var + 1e-5f);
  float4 g = *(const float4*)(gamma + c);
  float4 bb = *(const float4*)(beta + c);
  float gg[4] = {g.x, g.y, g.z, g.w};
  float bv[4] = {bb.x, bb.y, bb.z, bb.w};
  short4v o;
  for (int i = 0; i < 4; ++i)
    o[i] = f2bf((f[i] - mu) * rstd * gg[i] + bv[i]);
  *(short4v*)(h + (size_t)row * DIMD + c) = o;
}

// ===================== shared GEMM helpers =====================
__device__ __forceinline__ void rd_a(const short* base, int s0, int s1,
                                     short8 (&a)[4][2]) {
#pragma unroll
  for (int m = 0; m < 4; ++m) {
    a[m][0] = *(const short8*)(base + m*16*64 + s0);
    a[m][1] = *(const short8*)(base + m*16*64 + s1);
  }
}
__device__ __forceinline__ void rd_b(const short* base, int s0, int s1,
                                     short8 (&b)[2][2]) {
#pragma unroll
  for (int n = 0; n < 2; ++n) {
    b[n][0] = *(const short8*)(base + n*16*64 + s0);
    b[n][1] = *(const short8*)(base + n*16*64 + s1);
  }
}
template<int QM, int QN>
__device__ __forceinline__ void qmm(const short8 (&a)[4][2], const short8 (&b)[2][2],
                                    floatx4 (&acc)[8][4]) {
  __builtin_amdgcn_s_setprio(1);
#pragma unroll
  for (int m = 0; m < 4; ++m)
#pragma unroll
    for (int n = 0; n < 2; ++n) {
      floatx4 c = acc[QM*4+m][QN*2+n];
      c = __builtin_amdgcn_mfma_f32_16x16x32_bf16(a[m][0], b[n][0], c, 0, 0, 0);
      c = __builtin_amdgcn_mfma_f32_16x16x32_bf16(a[m][1], b[n][1], c, 0, 0, 0);
      acc[QM*4+m][QN*2+n] = c;
    }
  __builtin_amdgcn_s_setprio(0);
}
// 4x4 accumulator variant (128-row tile: single M quadrant)
template<int QN>
__device__ __forceinline__ void qmm2(const short8 (&a)[4][2], const short8 (&b)[2][2],
                                     floatx4 (&acc)[4][4]) {
  __builtin_amdgcn_s_setprio(1);
#pragma unroll
  for (int m = 0; m < 4; ++m)
#pragma unroll
    for (int n = 0; n < 2; ++n) {
      floatx4 c = acc[m][QN*2+n];
      c = __builtin_amdgcn_mfma_f32_16x16x32_bf16(a[m][0], b[n][0], c, 0, 0, 0);
      c = __builtin_amdgcn_mfma_f32_16x16x32_bf16(a[m][1], b[n][1], c, 0, 0, 0);
      acc[m][QN*2+n] = c;
    }
  __builtin_amdgcn_s_setprio(0);
}
// stage rows [0,128) of one matrix half-panel: 2 wave-level DMA calls
__device__ __forceinline__ void stg2(const short* p, int K, short* lds) {
  gl2lds16(p, lds);
  gl2lds16(p + (size_t)64*K, lds + 64*64);
}
// stage a full 256-row K-tile panel via two 128-row bases: 4 calls
__device__ __forceinline__ void stg4b(const short* p0, const short* p1, int K,
                                      short* lds, int koff) {
  stg2(p0 + koff, K, lds);
  stg2(p1 + koff, K, lds + 128*64);
}

// ===================== 256x256 read-ahead GEMM (GEMM1) =====================
// K-loop frozen at R2 state. R8: V col-blocks write V^T register-direct.
// R9: lin/pre col-blocks (bx>=12) are FUSED: W-panel = 128 lin rows
// (3072+c0..) U 128 pre rows (4096+c0..) - same DMA count, identical
// K-loop and vmcnt arithmetic. Epilogue computes branch = lin*gelu(pre)
// in-block (lin parked in dead staging LDS as bf16, pre-waves apply
// gelu) - BIT-IDENTICAL to the old proj->gelu_kernel path (same bf16
// roundings). Kills gelu kernel + 67MB of proj round-trip traffic.
__global__ __launch_bounds__(512, 2) void gemm256(const short* __restrict__ A,
    const short* __restrict__ W, short* __restrict__ C, short* __restrict__ VT,
    short* __restrict__ BR, int M, int N, int K) {
  __shared__ __align__(16) short SH[4*256*64];    // 128KB
  short* AsF = SH;
  short* WsF = SH + 2*256*64;
  const int tid = threadIdx.x;
  const int lane = tid & 63, wv = tid >> 6;
  const int wm = wv >> 2, wn = wv & 3;
  const int quad = lane >> 4, l16 = lane & 15;

  // bijective XCD swizzle (grid % 8 == 0)
  const int nbx = N >> 8;            // 20
  int cpx = gridDim.x >> 3;
  int orig = blockIdx.x;
  int wg = (orig & 7) * cpx + (orig >> 3);
  int bx = wg % nbx, by = wg / nbx;
  const int row0 = by << 8, col0 = bx << 8;
  const int blkty = (bx >= 12) ? 2 : ((bx >= 8) ? 1 : 0);  // 0:qk 1:V 2:fused
  const int c0 = (bx - 12) << 7;     // fused branch col base (valid when blkty==2)

  // staging: lane (lrow, sslot): LDS gets linear lane*16B; global source is
  // pre-swizzled so LDS[row][slot] holds global slot (slot ^ (row&7)).
  const int lrow = lane >> 3;
  const int sslot = (lane & 7) ^ lrow;
  const int wr0 = (blkty == 2) ? (3*DIMD + c0) : col0;        // W rows 0..127
  const int wr1 = (blkty == 2) ? (4*DIMD + c0) : (col0 + 128); // W rows 128..255
  const short* pA  = A + (size_t)(row0 + wv*8 + lrow) * K + sslot*8;
  const short* pW  = W + (size_t)(wr0 + wv*8 + lrow) * K + sslot*8;
  const short* pW2 = W + (size_t)(wr1 + wv*8 + lrow) * K + sslot*8;
  short* stA = AsF + wv*8*64;
  short* stW = WsF + wv*8*64;
  // read bases: row = (frag base + l16), slot = (kk*4+quad) ^ (l16&7)
  const short* aB = AsF + (wm*128 + l16)*64;
  const short* wB = WsF + (wn*64 + l16)*64;
  const int s0 = (quad ^ (l16 & 7)) << 3;
  const int s1 = s0 ^ 32;

  floatx4 acc[8][4] = {};
  short8 a[4][2], b0[2][2], b1[2][2];

  const int nktm = (K >> 6) - 1;   // K-tile index mask (power of 2 count)

  // prologue: tile0 (A+W) -> buf0; tile1 A -> buf1  (12 DMA calls)
  stg4b(pA, pA + (size_t)128*K, K, stA, 0);
  stg4b(pW, pW2, K, stW, 0);
  stg4b(pA, pA + (size_t)128*K, K, stA + 16384, 64);
  asm volatile("s_waitcnt vmcnt(4)" ::: "memory");   // tile0 complete
  wgbar();

  const int NT = K >> 6;
  for (int t = 0; t < NT; ++t) {
    const int cur = (t & 1) << 14;         // buffer offset in shorts (0 / 16384)
    const int nxt = cur ^ 16384;
    const int kw1 = ((t + 1) & nktm) << 6; // W prefetch k-offset
    const int ka2 = ((t + 2) & nktm) << 6; // A prefetch k-offset
    // ---- P1: read A-q0 + B-q0 of tile t; stage W(t+1) -> other buf ----
    rd_a(aB + cur, s0, s1, a);
    rd_b(wB + cur, s0, s1, b0);
    stg4b(pW, pW2, K, stW + nxt, kw1);
    wgbar();
    // ---- P2: MFMA quadrant (0,0); read B-q1 (consumed next phase) ----
    qmm<0,0>(a, b0, acc);
    rd_b(wB + cur + 32*64, s0, s1, b1);
    wgbar();
    // ---- P3: MFMA (0,1); read A-q1 into same frag regs (q0 dead) ----
    qmm<0,1>(a, b1, acc);
    rd_a(aB + cur + 64*64, s0, s1, a);
    wgbar();
    // ---- P4: MFMA (1,1) ----
    qmm<1,1>(a, b1, acc);
    wgbar();   // all A reads of tile t complete past this point
    // ---- P5: stage A(t+2) -> cur A-region (WAR-safe); MFMA (1,0);
    //          counted wait: A(t+1)+W(t+1) drained, A(t+2) in flight ----
    stg4b(pA + ka2, pA + (size_t)128*K + ka2, K, stA + cur, 0);
    qmm<1,0>(a, b0, acc);
    asm volatile("s_waitcnt vmcnt(4)" ::: "memory");
    wgbar();
  }
  asm volatile("s_waitcnt vmcnt(0)" ::: "memory");

  if (blkty == 0) {
    // epilogue: rows (wm*128 + i*16 + quad*4 + r), cols (wn*64 + j*16 + l16)
#pragma unroll
    for (int i = 0; i < 8; ++i) {
      int r0 = row0 + wm*128 + i*16 + quad*4;
#pragma unroll
      for (int j = 0; j < 4; ++j) {
        int cc = col0 + wn*64 + j*16 + l16;
#pragma unroll
        for (int r = 0; r < 4; ++r)
          C[(size_t)(r0 + r) * N + cc] = f2bf(acc[i][j][r]);
      }
    }
  } else if (blkty == 1) {
    // register-direct V^T write: VT[(bb*8+hh)*128+dd][l], 8B stores.
    int grow = row0 + wm*128;
    int bb = grow >> 11, lbase = grow & 2047;
#pragma unroll
    for (int j = 0; j < 4; ++j) {
      int dg = col0 - 2*DIMD + wn*64 + j*16 + l16;   // 0..1023
      short* dcol = VT + (((size_t)(bb*NHEAD + (dg >> 7))*HD + (dg & 127))*LSEQ
                          + lbase + quad*4);
#pragma unroll
      for (int i = 0; i < 8; ++i) {
        short4v p;
#pragma unroll
        for (int r = 0; r < 4; ++r) p[r] = f2bf(acc[i][j][r]);
        *(short4v*)(dcol + i*16) = p;
      }
    }
  } else {
    // fused gelu epilogue. acc cols 0..127 = lin, 128..255 = pre.
    wgbar();   // every wave past its vmcnt(0): all DMA into LDS retired
    short* G = SH;   // bf16 lin park: G[256][132]
    if ((wn & 2) == 0) {
      int colb = wn*64;
#pragma unroll
      for (int i = 0; i < 8; ++i) {
        int row = wm*128 + i*16 + quad*4;
#pragma unroll
        for (int j = 0; j < 4; ++j) {
          int cl = colb + j*16 + l16;
#pragma unroll
          for (int r = 0; r < 4; ++r)
            G[(row + r)*132 + cl] = f2bf(acc[i][j][r]);
        }
      }
    }
    wgbar();
    if (wn & 2) {
      int colb = (wn - 2)*64;
#pragma unroll
      for (int i = 0; i < 8; ++i) {
        int row = wm*128 + i*16 + quad*4;
#pragma unroll
        for (int j = 0; j < 4; ++j) {
          int cl = colb + j*16 + l16;
#pragma unroll
          for (int r = 0; r < 4; ++r) {
            float pre = bf2f(f2bf(acc[i][j][r]));   // bf16 round-trip = old proj path
            float g = 0.5f * pre * (1.f + erff(pre * 0.70710678118654752f));
            float lin = bf2f(G[(row + r)*132 + cl]);
            BR[(size_t)(row0 + row + r) * BRC + c0 + cl] = f2bf(lin * g);
          }
        }
      }
    }
  }
}

// ===================== GEMM2: 128x256 single-round =====================
// out[M,N] = branch[M,K] * wo[N,K]^T + X, fp32 out. 256 blocks = 1 round.
__global__ __launch_bounds__(512, 2) void gemm2(const short* __restrict__ A,
    const short* __restrict__ W, const float* __restrict__ X,
    float* __restrict__ out, int M, int N, int K) {
  __shared__ __align__(16) short As2[2*128*64];   // 32KB
  __shared__ __align__(16) short Ws2[2*256*64];   // 64KB
  const int tid = threadIdx.x;
  const int lane = tid & 63, wv = tid >> 6;
  const int wm = wv >> 2, wn = wv & 3;            // wm: 2x64 rows, wn: 4x64 cols
  const int quad = lane >> 4, l16 = lane & 15;

  const int nbx = N >> 8;                          // 4 col-blocks
  int cpx = gridDim.x >> 3;                        // 32
  int orig = blockIdx.x;
  int wg = (orig & 7) * cpx + (orig >> 3);
  int bx = wg % nbx, by = wg / nbx;
  const int row0 = by << 7, col0 = bx << 8;

  const int lrow = lane >> 3;
  const int sslot = (lane & 7) ^ lrow;
  const short* pA = A + (size_t)(row0 + wv*8 + lrow) * K + sslot*8;
  const short* pW = W + (size_t)(col0 + wv*8 + lrow) * K + sslot*8;
  short* stA = As2 + wv*8*64;
  short* stW = Ws2 + wv*8*64;
  const short* aB = As2 + (wm*64 + l16)*64;
  const short* wB = Ws2 + (wn*64 + l16)*64;
  const int s0 = (quad ^ (l16 & 7)) << 3;
  const int s1 = s0 ^ 32;

  floatx4 acc[4][4] = {};
  short8 a[4][2], b0[2][2], b1[2][2];

  const int nktm = (K >> 6) - 1;   // 31 (power-of-2 tile count)

  // prologue: tile0 A+W -> buf0 (6 calls); tile1 A -> buf1 (2 calls)
  stg2(pA, K, stA);
  stg2(pW, K, stW);
  stg2(pW + (size_t)128*K, K, stW + 128*64);
  stg2(pA + 64, K, stA + 8192);
  asm volatile("s_waitcnt vmcnt(2)" ::: "memory");  // tile0 complete
  wgbar();

  const int NT = K >> 6;           // 32
  for (int t = 0; t < NT; ++t) {
    const int curA = (t & 1) << 13;        // 0 / 8192
    const int curW = (t & 1) << 14;        // 0 / 16384
    const int nxtW = curW ^ 16384;
    const int kw1 = ((t + 1) & nktm) << 6;
    const int ka2 = ((t + 2) & nktm) << 6;
    // ---- P1: read a (8) + b0 (4); stage W(t+1) -> other buf (4 DMA) ----
    rd_a(aB + curA, s0, s1, a);
    rd_b(wB + curW, s0, s1, b0);
    stg2(pW + kw1, K, stW + nxtW);
    stg2(pW + (size_t)128*K + kw1, K, stW + nxtW + 128*64);
    wgbar();
    // ---- P2: MFMA cluster 0 (a x b0, 16); read b1 ----
    qmm2<0>(a, b0, acc);
    rd_b(wB + curW + 32*64, s0, s1, b1);
    wgbar();
    // ---- P3: stage A(t+2) -> cur A (WAR-safe: a consumed by P2-end);
    //          MFMA cluster 1; counted wait A(t+1)+W(t+1) ----
    stg2(pA + ka2, K, stA + curA);
    qmm2<1>(a, b1, acc);
    asm volatile("s_waitcnt vmcnt(2)" ::: "memory");
    wgbar();
  }
  asm volatile("s_waitcnt vmcnt(0)" ::: "memory");

  // epilogue: rows wm*64 + i*16 + quad*4 + r, cols wn*64 + j*16 + l16
#pragma unroll
  for (int i = 0; i < 4; ++i) {
    int r0 = row0 + wm*64 + i*16 + quad*4;
#pragma unroll
    for (int j = 0; j < 4; ++j) {
      int cc = col0 + wn*64 + j*16 + l16;
#pragma unroll
      for (int r = 0; r < 4; ++r) {
        size_t idx = (size_t)(r0 + r) * N + cc;
        out[idx] = acc[i][j][r] + X[idx];
      }
    }
  }
}

// ------------- Flash attention, p=2 power-softmax, causal.
// R3 structure: adjacent-tile pairing (util ~96%), complementary dispatch
// (CU gets gsel=gx and 15-gx -> uniform 34 steps), T14 K/V prefetch,
// setprio around MFMA clusters. V^T read from materialized vt (d_out).
__global__ __launch_bounds__(512) void attn_kernel(const short* __restrict__ proj,
    const short* __restrict__ vt, short* __restrict__ branch) {
  int bh = blockIdx.y;
  int b = bh >> 3, hh = bh & 7;
  int gx = blockIdx.x;             // 0..15
  int gsel = (bh < 16) ? gx : (15 - gx);
  int tid = threadIdx.x;           // 0..511
  int wv = tid >> 6, lane = tid & 63, quad = lane >> 4, l16 = lane & 15;
  int qsel = 2*gsel + ((wv < 4) ? 0 : 1);
  int qw = qsel * 64 + (wv & 3) * 16;

  const short* Qp  = proj + (size_t)b * LSEQ * PROJC + hh*HD;
  const short* Kp  = Qp + DIMD;
  const short* VTp = vt + (size_t)bh * HD * LSEQ;

  __shared__ short Ks[64][136];
  __shared__ short Vs[128][76];
  __shared__ short Ps[8][16][44];

  short8 qf[4];
  {
    const short* qrow = Qp + (size_t)(qw + l16) * PROJC;
    for (int s = 0; s < 4; ++s) qf[s] = *(const short8*)(qrow + s*32 + quad*8);
  }
  float lsum[4] = {0.f, 0.f, 0.f, 0.f};
  floatx4 O[8] = {};

  const float scale = 0.08838834764831845f;  // 1/sqrt(128)
  int NT = 2*gsel + 2;             // staged 64-wide tiles
  int krow = tid >> 4;             // 0..31
  int kcol = (tid & 15) * 8;
  int vd = tid >> 2;               // 0..127
  int vk = (tid & 3) * 8;

  // prefetch of tile 0
  short8 kv0 = *(const short8*)(Kp + (size_t)(krow) * PROJC + kcol);
  short8 kv1 = *(const short8*)(Kp + (size_t)(32 + krow) * PROJC + kcol);
  short8 vv0 = *(const short8*)(VTp + (size_t)vd * LSEQ + vk);
  short8 vv1 = *(const short8*)(VTp + (size_t)vd * LSEQ + 32 + vk);

  for (int kt = 0; kt < NT; ++kt) {
    int kb64 = kt * 64;
    __syncthreads();
    *(short8*)&Ks[krow][kcol]      = kv0;
    *(short8*)&Ks[krow + 32][kcol] = kv1;
    *(short8*)&Vs[vd][vk]          = vv0;
    *(short8*)&Vs[vd][32 + vk]     = vv1;
    // T14: issue next tile's loads now; they fly during this tile's compute.
    {
      int ktn = (kt + 1 < NT) ? (kt + 1) : kt;   // clamped (last iter: dummy)
      int kb64n = ktn * 64;
      kv0 = *(const short8*)(Kp + (size_t)(kb64n + krow) * PROJC + kcol);
      kv1 = *(const short8*)(Kp + (size_t)(kb64n + 32 + krow) * PROJC + kcol);
      vv0 = *(const short8*)(VTp + (size_t)vd * LSEQ + kb64n + vk);
      vv1 = *(const short8*)(VTp + (size_t)vd * LSEQ + kb64n + 32 + vk);
    }
    __syncthreads();
    for (int hf = 0; hf < 2; ++hf) {
      int kb = kb64 + hf*32;
      if (kb <= qw + 15) {
        floatx4 s0 = {0.f,0.f,0.f,0.f}, s1 = {0.f,0.f,0.f,0.f};
        __builtin_amdgcn_s_setprio(1);
        for (int s = 0; s < 4; ++s) {
          short8 kf0 = *(const short8*)&Ks[hf*32 + l16][s*32 + quad*8];
          short8 kf1 = *(const short8*)&Ks[hf*32 + 16 + l16][s*32 + quad*8];
          s0 = __builtin_amdgcn_mfma_f32_16x16x32_bf16(qf[s], kf0, s0, 0, 0, 0);
          s1 = __builtin_amdgcn_mfma_f32_16x16x32_bf16(qf[s], kf1, s1, 0, 0, 0);
        }
        __builtin_amdgcn_s_setprio(0);
        int c0 = kb + l16, c1 = kb + 16 + l16;
        for (int r = 0; r < 4; ++r) {
          int q = qw + quad*4 + r;
          float w0 = (c0 <= q) ? __expf(s0[r] * scale) : 0.f;
          float w1 = (c1 <= q) ? __expf(s1[r] * scale) : 0.f;
          lsum[r] += w0*w0 + w1*w1;
          Ps[wv][quad*4+r][l16]      = f2bf(w0);
          Ps[wv][quad*4+r][16 + l16] = f2bf(w1);
        }
        asm volatile("s_waitcnt lgkmcnt(0)" ::: "memory");
        short8 pf = *(const short8*)&Ps[wv][l16][quad*8];
        __builtin_amdgcn_s_setprio(1);
        for (int t8 = 0; t8 < 8; ++t8) {
          short8 vf = *(const short8*)&Vs[t8*16 + l16][hf*32 + quad*8];
          O[t8] = __builtin_amdgcn_mfma_f32_16x16x32_bf16(pf, vf, O[t8], 0, 0, 0);
        }
        __builtin_amdgcn_s_setprio(0);
      }
    }
  }
  for (int r = 0; r < 4; ++r) {
    float l = lsum[r];
    for (int off = 1; off < 16; off <<= 1) l += __shfl_xor(l, off);
    float inv = rsqrtf(l);
    int q = qw + quad*4 + r;
    short* orow = branch + ((size_t)(b*LSEQ + q)) * BRC + DIMD + hh*HD;
    for (int t8 = 0; t8 < 8; ++t8)
      orow[t8*16 + l16] = f2bf(O[t8][r] * inv);
  }
}

extern "C" void kernel_launch(void* const* d_in, const int* in_sizes, int n_in,
                              void* d_out, int out_size, void* d_ws, size_t ws_size,
                              hipStream_t stream) {
  const float* x     = (const float*)d_in[0];
  const float* gamma = (const float*)d_in[1];
  const float* beta  = (const float*)d_in[2];
  const float* w_qkv = (const float*)d_in[3];
  const float* w_out = (const float*)d_in[4];
  float* out = (float*)d_out;

  char* ws = (char*)d_ws;
  short* h      = (short*)ws;                                 // 16 MB
  short* proj   = (short*)(ws + (size_t)16*1024*1024);        // 80 MB (q,k,v slices used)
  short* branch = (short*)(ws + (size_t)96*1024*1024);        // 32 MB
  short* wq     = (short*)(ws + (size_t)128*1024*1024);       // 10 MB
  short* wo     = (short*)(ws + (size_t)138*1024*1024);       // 4 MB
  short* vt     = (short*)out;  // V^T in d_out (dead until gemm2 writes it)

  int n1 = PROJC*DIMD/4, n2 = DIMD*BRC/4;
  int nblk_cvt = (n1 + n2 + 255)/256;
  pre_kernel<<<nblk_cvt + NROWS, 256, 0, stream>>>(x, gamma, beta, h,
                                                   w_qkv, wq, n1, w_out, wo, n2,
                                                   nblk_cvt);
  gemm256<<<dim3((NROWS/256)*(PROJC/256)), 512, 0, stream>>>(h, wq, proj, vt,
                                                             branch,
                                                             NROWS, PROJC, DIMD);
  attn_kernel<<<dim3(16, BATCH*NHEAD), 512, 0, stream>>>(proj, vt, branch);
  gemm2<<<dim3(256), 512, 0, stream>>>(branch, wo, x, out, NROWS, DIMD, BRC);
}

// Round 10
// 310.594 us; speedup vs baseline: 1.0971x; 1.0971x over previous
//
#include <hip/hip_runtime.h>
#include <hip/hip_bf16.h>
#include <math.h>

#define DIMD 1024
#define LSEQ 2048
#define BATCH 4
#define NHEAD 8
#define HD 128
#define NROWS (BATCH*LSEQ)   // 8192
#define PROJC (5*DIMD)       // 5120
#define BRC (2*DIMD)         // 2048

typedef __attribute__((ext_vector_type(8))) short short8;
typedef __attribute__((ext_vector_type(4))) short short4v;
typedef __attribute__((ext_vector_type(4))) float floatx4;

__device__ __forceinline__ float bf2f(short s) {
  unsigned int u = ((unsigned int)(unsigned short)s) << 16;
  return __builtin_bit_cast(float, u);
}
__device__ __forceinline__ short f2bf(float f) {
  unsigned int u = __builtin_bit_cast(unsigned int, f);
  unsigned int lsb = (u >> 16) & 1u;
  u += 0x7fffu + lsb;
  return (short)(u >> 16);
}

// global->LDS direct DMA, 16B per lane. LDS dest is wave-uniform base;
// HW scatters lane i to lds + i*16. Global source is PER-LANE (exploited
// by the fused W staging below).
__device__ __forceinline__ void gl2lds16(const short* g, short* l) {
  __builtin_amdgcn_global_load_lds(
      (const __attribute__((address_space(1))) unsigned int*)(unsigned long long)g,
      (__attribute__((address_space(3))) unsigned int*)(unsigned int)(unsigned long long)l,
      16, 0, 0);
}

__device__ __forceinline__ void wgbar() {
  asm volatile("" ::: "memory");
  __builtin_amdgcn_s_barrier();
  asm volatile("" ::: "memory");
}

// ------- fused weight-convert (fp32->bf16) + LayerNorm (x -> h bf16) -------
__global__ __launch_bounds__(256) void pre_kernel(
    const float* __restrict__ x, const float* __restrict__ gamma,
    const float* __restrict__ beta, short* __restrict__ h,
    const float* __restrict__ s1, short* __restrict__ d1, int n1_4,
    const float* __restrict__ s2, short* __restrict__ d2, int n2_4,
    int nblk_cvt) {
  int bid = blockIdx.x;
  if (bid < nblk_cvt) {
    int i = bid * 256 + threadIdx.x;
    const float* src; short* dst;
    if (i < n1_4) { src = s1; dst = d1; }
    else { i -= n1_4; if (i >= n2_4) return; src = s2; dst = d2; }
    float4 v = *(const float4*)(src + (size_t)i * 4);
    short4v o;
    o[0] = f2bf(v.x); o[1] = f2bf(v.y); o[2] = f2bf(v.z); o[3] = f2bf(v.w);
    *(short4v*)(dst + (size_t)i * 4) = o;
    return;
  }
  int row = bid - nblk_cvt;
  int c = threadIdx.x * 4;
  const float* xr = x + (size_t)row * DIMD;
  float4 v = *(const float4*)(xr + c);
  float f[4] = {v.x, v.y, v.z, v.w};
  float sum = 0.f, sq = 0.f;
  for (int i = 0; i < 4; ++i) { sum += f[i]; sq += f[i]*f[i]; }
  for (int off = 1; off < 64; off <<= 1) {
    sum += __shfl_xor(sum, off);
    sq  += __shfl_xor(sq, off);
  }
  __shared__ float red[8];
  int wid = threadIdx.x >> 6;
  if ((threadIdx.x & 63) == 0) { red[wid*2] = sum; red[wid*2+1] = sq; }
  __syncthreads();
  sum = red[0]+red[2]+red[4]+red[6];
  sq  = red[1]+red[3]+red[5]+red[7];
  float mu = sum * (1.0f/DIMD);
  float var = sq * (1.0f/DIMD) - mu*mu;
  float rstd = rsqrtf(var + 1e-5f);
  float4 g = *(const float4*)(gamma + c);
  float4 bb = *(const float4*)(beta + c);
  float gg[4] = {g.x, g.y, g.z, g.w};
  float bv[4] = {bb.x, bb.y, bb.z, bb.w};
  short4v o;
  for (int i = 0; i < 4; ++i)
    o[i] = f2bf((f[i] - mu) * rstd * gg[i] + bv[i]);
  *(short4v*)(h + (size_t)row * DIMD + c) = o;
}

// ===================== shared GEMM helpers =====================
__device__ __forceinline__ void rd_a(const short* base, int s0, int s1,
                                     short8 (&a)[4][2]) {
#pragma unroll
  for (int m = 0; m < 4; ++m) {
    a[m][0] = *(const short8*)(base + m*16*64 + s0);
    a[m][1] = *(const short8*)(base + m*16*64 + s1);
  }
}
__device__ __forceinline__ void rd_b(const short* base, int s0, int s1,
                                     short8 (&b)[2][2]) {
#pragma unroll
  for (int n = 0; n < 2; ++n) {
    b[n][0] = *(const short8*)(base + n*16*64 + s0);
    b[n][1] = *(const short8*)(base + n*16*64 + s1);
  }
}
template<int QM, int QN>
__device__ __forceinline__ void qmm(const short8 (&a)[4][2], const short8 (&b)[2][2],
                                    floatx4 (&acc)[8][4]) {
  __builtin_amdgcn_s_setprio(1);
#pragma unroll
  for (int m = 0; m < 4; ++m)
#pragma unroll
    for (int n = 0; n < 2; ++n) {
      floatx4 c = acc[QM*4+m][QN*2+n];
      c = __builtin_amdgcn_mfma_f32_16x16x32_bf16(a[m][0], b[n][0], c, 0, 0, 0);
      c = __builtin_amdgcn_mfma_f32_16x16x32_bf16(a[m][1], b[n][1], c, 0, 0, 0);
      acc[QM*4+m][QN*2+n] = c;
    }
  __builtin_amdgcn_s_setprio(0);
}
// 4x4 accumulator variant (128-row tile: single M quadrant)
template<int QN>
__device__ __forceinline__ void qmm2(const short8 (&a)[4][2], const short8 (&b)[2][2],
                                     floatx4 (&acc)[4][4]) {
  __builtin_amdgcn_s_setprio(1);
#pragma unroll
  for (int m = 0; m < 4; ++m)
#pragma unroll
    for (int n = 0; n < 2; ++n) {
      floatx4 c = acc[m][QN*2+n];
      c = __builtin_amdgcn_mfma_f32_16x16x32_bf16(a[m][0], b[n][0], c, 0, 0, 0);
      c = __builtin_amdgcn_mfma_f32_16x16x32_bf16(a[m][1], b[n][1], c, 0, 0, 0);
      acc[m][QN*2+n] = c;
    }
  __builtin_amdgcn_s_setprio(0);
}
// stage rows [0,128) of one matrix half-panel: 2 wave-level DMA calls
__device__ __forceinline__ void stg2(const short* p, int K, short* lds) {
  gl2lds16(p, lds);
  gl2lds16(p + (size_t)64*K, lds + 64*64);
}
// stage a full 256-row K-tile panel via two 128-row bases: 4 calls
__device__ __forceinline__ void stg4b(const short* p0, const short* p1, int K,
                                      short* lds, int koff) {
  stg2(p0 + koff, K, lds);
  stg2(p1 + koff, K, lds + 128*64);
}

// ===================== 256x256 read-ahead GEMM (GEMM1) =====================
// K-loop frozen at R2 state. R8: V col-blocks write V^T register-direct.
// R10 fused gelu v2: lin/pre col-blocks (bx>=12) stage an INTERLEAVED
// W-panel (per-lane global src: each 64-row wn-block = 32 lin rows +
// 32 pre rows) -> acc[i][j] (lin) and acc[i][j+2] (pre) hold the SAME
// branch column IN THE SAME LANE. Epilogue = pure in-lane math: 64 erff
// + 64 2B stores, no barrier/LDS/idle waves (fixes R9's two-phase
// epilogue, -33us). Staging call count / vmcnt arithmetic IDENTICAL to
// the frozen K-loop. Bit-identical numerics to the old gelu_kernel path.
__global__ __launch_bounds__(512, 2) void gemm256(const short* __restrict__ A,
    const short* __restrict__ W, short* __restrict__ C, short* __restrict__ VT,
    short* __restrict__ BR, int M, int N, int K) {
  __shared__ __align__(16) short AsF[2*256*64];   // 64KB (2 bufs)
  __shared__ __align__(16) short WsF[2*256*64];   // 64KB
  const int tid = threadIdx.x;
  const int lane = tid & 63, wv = tid >> 6;
  const int wm = wv >> 2, wn = wv & 3;
  const int quad = lane >> 4, l16 = lane & 15;

  // bijective XCD swizzle (grid % 8 == 0)
  const int nbx = N >> 8;            // 20
  int cpx = gridDim.x >> 3;
  int orig = blockIdx.x;
  int wg = (orig & 7) * cpx + (orig >> 3);
  int bx = wg % nbx, by = wg / nbx;
  const int row0 = by << 8, col0 = bx << 8;
  const int blkty = (bx >= 12) ? 2 : ((bx >= 8) ? 1 : 0);  // 0:qk 1:V 2:fused
  const int c0 = (bx - 12) << 7;     // fused branch col base (blkty==2)

  // staging: lane (lrow, sslot): LDS gets linear lane*16B; global source is
  // pre-swizzled so LDS[row][slot] holds global slot (slot ^ (row&7)).
  const int lrow = lane >> 3;
  const int sslot = (lane & 7) ^ lrow;
  const bool fused = (blkty == 2);
  const short* pA  = A + (size_t)(row0 + wv*8 + lrow) * K + sslot*8;
  const short* pW  = W + (size_t)(col0 + wv*8 + lrow) * K + sslot*8;
  const short* pW2 = W + (size_t)(col0 + 128 + wv*8 + lrow) * K + sslot*8;
  // fused W base: panel row (c*64 + wv*8 + lrow) <- W row
  //   (wv<4 ? lin : pre) + c0 + c*32 + ((wv*8+lrow)&31)
  const int tq = (wv*8 + lrow) & 31;
  const short* pWf = W + (size_t)((wv < 4 ? 3*DIMD : 4*DIMD) + c0 + tq) * K
                       + sslot*8;
  short* stA = AsF + wv*8*64;
  short* stW = WsF + wv*8*64;
  // read bases: row = (frag base + l16), slot = (kk*4+quad) ^ (l16&7)
  const short* aB = AsF + (wm*128 + l16)*64;
  const short* wB = WsF + (wn*64 + l16)*64;
  const int s0 = (quad ^ (l16 & 7)) << 3;
  const int s1 = s0 ^ 32;

  auto stgW = [&](short* dst, int koff) {
    if (fused) {
      gl2lds16(pWf + koff, dst);
      gl2lds16(pWf + (size_t)32*K + koff, dst + 64*64);
      gl2lds16(pWf + (size_t)64*K + koff, dst + 128*64);
      gl2lds16(pWf + (size_t)96*K + koff, dst + 192*64);
    } else {
      stg4b(pW, pW2, K, dst, koff);
    }
  };

  floatx4 acc[8][4] = {};
  short8 a[4][2], b0[2][2], b1[2][2];

  const int nktm = (K >> 6) - 1;   // K-tile index mask (power of 2 count)

  // prologue: tile0 (A+W) -> buf0; tile1 A -> buf1  (12 DMA calls)
  stg4b(pA, pA + (size_t)128*K, K, stA, 0);
  stgW(stW, 0);
  stg4b(pA, pA + (size_t)128*K, K, stA + 16384, 64);
  asm volatile("s_waitcnt vmcnt(4)" ::: "memory");   // tile0 complete
  wgbar();

  const int NT = K >> 6;
  for (int t = 0; t < NT; ++t) {
    const int cur = (t & 1) << 14;         // buffer offset in shorts (0 / 16384)
    const int nxt = cur ^ 16384;
    const int kw1 = ((t + 1) & nktm) << 6; // W prefetch k-offset
    const int ka2 = ((t + 2) & nktm) << 6; // A prefetch k-offset
    // ---- P1: read A-q0 + B-q0 of tile t; stage W(t+1) -> other buf ----
    rd_a(aB + cur, s0, s1, a);
    rd_b(wB + cur, s0, s1, b0);
    stgW(stW + nxt, kw1);
    wgbar();
    // ---- P2: MFMA quadrant (0,0); read B-q1 (consumed next phase) ----
    qmm<0,0>(a, b0, acc);
    rd_b(wB + cur + 32*64, s0, s1, b1);
    wgbar();
    // ---- P3: MFMA (0,1); read A-q1 into same frag regs (q0 dead) ----
    qmm<0,1>(a, b1, acc);
    rd_a(aB + cur + 64*64, s0, s1, a);
    wgbar();
    // ---- P4: MFMA (1,1) ----
    qmm<1,1>(a, b1, acc);
    wgbar();   // all A reads of tile t complete past this point
    // ---- P5: stage A(t+2) -> cur A-region (WAR-safe); MFMA (1,0);
    //          counted wait: A(t+1)+W(t+1) drained, A(t+2) in flight ----
    stg4b(pA, pA + (size_t)128*K, K, stA + cur, ka2);
    qmm<1,0>(a, b0, acc);
    asm volatile("s_waitcnt vmcnt(4)" ::: "memory");
    wgbar();
  }
  asm volatile("s_waitcnt vmcnt(0)" ::: "memory");

  if (blkty == 0) {
    // epilogue: rows (wm*128 + i*16 + quad*4 + r), cols (wn*64 + j*16 + l16)
#pragma unroll
    for (int i = 0; i < 8; ++i) {
      int r0 = row0 + wm*128 + i*16 + quad*4;
#pragma unroll
      for (int j = 0; j < 4; ++j) {
        int cc = col0 + wn*64 + j*16 + l16;
#pragma unroll
        for (int r = 0; r < 4; ++r)
          C[(size_t)(r0 + r) * N + cc] = f2bf(acc[i][j][r]);
      }
    }
  } else if (blkty == 1) {
    // register-direct V^T write: VT[(bb*8+hh)*128+dd][l], 8B stores.
    int grow = row0 + wm*128;
    int bb = grow >> 11, lbase = grow & 2047;
#pragma unroll
    for (int j = 0; j < 4; ++j) {
      int dg = col0 - 2*DIMD + wn*64 + j*16 + l16;   // 0..1023
      short* dcol = VT + (((size_t)(bb*NHEAD + (dg >> 7))*HD + (dg & 127))*LSEQ
                          + lbase + quad*4);
#pragma unroll
      for (int i = 0; i < 8; ++i) {
        short4v p;
#pragma unroll
        for (int r = 0; r < 4; ++r) p[r] = f2bf(acc[i][j][r]);
        *(short4v*)(dcol + i*16) = p;
      }
    }
  } else {
    // fused gelu epilogue, pure in-lane: acc[i][j]=lin, acc[i][j+2]=pre
    // for branch col c0 + wn*32 + j*16 + l16. bf16 round-trip on both
    // operands = bit-identical to the old proj->gelu_kernel path.
#pragma unroll
    for (int i = 0; i < 8; ++i) {
      int r0 = row0 + wm*128 + i*16 + quad*4;
#pragma unroll
      for (int j = 0; j < 2; ++j) {
        int cc = c0 + wn*32 + j*16 + l16;
#pragma unroll
        for (int r = 0; r < 4; ++r) {
          float lin = bf2f(f2bf(acc[i][j][r]));
          float pre = bf2f(f2bf(acc[i][j+2][r]));
          float g = 0.5f * pre * (1.f + erff(pre * 0.70710678118654752f));
          BR[(size_t)(r0 + r) * BRC + cc] = f2bf(lin * g);
        }
      }
    }
  }
}

// ===================== GEMM2: 128x256 single-round =====================
// out[M,N] = branch[M,K] * wo[N,K]^T + X, fp32 out. 256 blocks = 1 round.
__global__ __launch_bounds__(512, 2) void gemm2(const short* __restrict__ A,
    const short* __restrict__ W, const float* __restrict__ X,
    float* __restrict__ out, int M, int N, int K) {
  __shared__ __align__(16) short As2[2*128*64];   // 32KB
  __shared__ __align__(16) short Ws2[2*256*64];   // 64KB
  const int tid = threadIdx.x;
  const int lane = tid & 63, wv = tid >> 6;
  const int wm = wv >> 2, wn = wv & 3;            // wm: 2x64 rows, wn: 4x64 cols
  const int quad = lane >> 4, l16 = lane & 15;

  const int nbx = N >> 8;                          // 4 col-blocks
  int cpx = gridDim.x >> 3;                        // 32
  int orig = blockIdx.x;
  int wg = (orig & 7) * cpx + (orig >> 3);
  int bx = wg % nbx, by = wg / nbx;
  const int row0 = by << 7, col0 = bx << 8;

  const int lrow = lane >> 3;
  const int sslot = (lane & 7) ^ lrow;
  const short* pA = A + (size_t)(row0 + wv*8 + lrow) * K + sslot*8;
  const short* pW = W + (size_t)(col0 + wv*8 + lrow) * K + sslot*8;
  short* stA = As2 + wv*8*64;
  short* stW = Ws2 + wv*8*64;
  const short* aB = As2 + (wm*64 + l16)*64;
  const short* wB = Ws2 + (wn*64 + l16)*64;
  const int s0 = (quad ^ (l16 & 7)) << 3;
  const int s1 = s0 ^ 32;

  floatx4 acc[4][4] = {};
  short8 a[4][2], b0[2][2], b1[2][2];

  const int nktm = (K >> 6) - 1;   // 31 (power-of-2 tile count)

  // prologue: tile0 A+W -> buf0 (6 calls); tile1 A -> buf1 (2 calls)
  stg2(pA, K, stA);
  stg2(pW, K, stW);
  stg2(pW + (size_t)128*K, K, stW + 128*64);
  stg2(pA + 64, K, stA + 8192);
  asm volatile("s_waitcnt vmcnt(2)" ::: "memory");  // tile0 complete
  wgbar();

  const int NT = K >> 6;           // 32
  for (int t = 0; t < NT; ++t) {
    const int curA = (t & 1) << 13;        // 0 / 8192
    const int curW = (t & 1) << 14;        // 0 / 16384
    const int nxtW = curW ^ 16384;
    const int kw1 = ((t + 1) & nktm) << 6;
    const int ka2 = ((t + 2) & nktm) << 6;
    // ---- P1: read a (8) + b0 (4); stage W(t+1) -> other buf (4 DMA) ----
    rd_a(aB + curA, s0, s1, a);
    rd_b(wB + curW, s0, s1, b0);
    stg2(pW + kw1, K, stW + nxtW);
    stg2(pW + (size_t)128*K + kw1, K, stW + nxtW + 128*64);
    wgbar();
    // ---- P2: MFMA cluster 0 (a x b0, 16); read b1 ----
    qmm2<0>(a, b0, acc);
    rd_b(wB + curW + 32*64, s0, s1, b1);
    wgbar();
    // ---- P3: stage A(t+2) -> cur A (WAR-safe: a consumed by P2-end);
    //          MFMA cluster 1; counted wait A(t+1)+W(t+1) ----
    stg2(pA + ka2, K, stA + curA);
    qmm2<1>(a, b1, acc);
    asm volatile("s_waitcnt vmcnt(2)" ::: "memory");
    wgbar();
  }
  asm volatile("s_waitcnt vmcnt(0)" ::: "memory");

  // epilogue: rows wm*64 + i*16 + quad*4 + r, cols wn*64 + j*16 + l16
#pragma unroll
  for (int i = 0; i < 4; ++i) {
    int r0 = row0 + wm*64 + i*16 + quad*4;
#pragma unroll
    for (int j = 0; j < 4; ++j) {
      int cc = col0 + wn*64 + j*16 + l16;
#pragma unroll
      for (int r = 0; r < 4; ++r) {
        size_t idx = (size_t)(r0 + r) * N + cc;
        out[idx] = acc[i][j][r] + X[idx];
      }
    }
  }
}

// ------------- Flash attention, p=2 power-softmax, causal.
// R3 structure: adjacent-tile pairing (util ~96%), complementary dispatch
// (CU gets gsel=gx and 15-gx -> uniform 34 steps), T14 K/V prefetch,
// setprio around MFMA clusters. V^T read from materialized vt (d_out).
__global__ __launch_bounds__(512) void attn_kernel(const short* __restrict__ proj,
    const short* __restrict__ vt, short* __restrict__ branch) {
  int bh = blockIdx.y;
  int b = bh >> 3, hh = bh & 7;
  int gx = blockIdx.x;             // 0..15
  int gsel = (bh < 16) ? gx : (15 - gx);
  int tid = threadIdx.x;           // 0..511
  int wv = tid >> 6, lane = tid & 63, quad = lane >> 4, l16 = lane & 15;
  int qsel = 2*gsel + ((wv < 4) ? 0 : 1);
  int qw = qsel * 64 + (wv & 3) * 16;

  const short* Qp  = proj + (size_t)b * LSEQ * PROJC + hh*HD;
  const short* Kp  = Qp + DIMD;
  const short* VTp = vt + (size_t)bh * HD * LSEQ;

  __shared__ short Ks[64][136];
  __shared__ short Vs[128][76];
  __shared__ short Ps[8][16][44];

  short8 qf[4];
  {
    const short* qrow = Qp + (size_t)(qw + l16) * PROJC;
    for (int s = 0; s < 4; ++s) qf[s] = *(const short8*)(qrow + s*32 + quad*8);
  }
  float lsum[4] = {0.f, 0.f, 0.f, 0.f};
  floatx4 O[8] = {};

  const float scale = 0.08838834764831845f;  // 1/sqrt(128)
  int NT = 2*gsel + 2;             // staged 64-wide tiles
  int krow = tid >> 4;             // 0..31
  int kcol = (tid & 15) * 8;
  int vd = tid >> 2;               // 0..127
  int vk = (tid & 3) * 8;

  // prefetch of tile 0
  short8 kv0 = *(const short8*)(Kp + (size_t)(krow) * PROJC + kcol);
  short8 kv1 = *(const short8*)(Kp + (size_t)(32 + krow) * PROJC + kcol);
  short8 vv0 = *(const short8*)(VTp + (size_t)vd * LSEQ + vk);
  short8 vv1 = *(const short8*)(VTp + (size_t)vd * LSEQ + 32 + vk);

  for (int kt = 0; kt < NT; ++kt) {
    int kb64 = kt * 64;
    __syncthreads();
    *(short8*)&Ks[krow][kcol]      = kv0;
    *(short8*)&Ks[krow + 32][kcol] = kv1;
    *(short8*)&Vs[vd][vk]          = vv0;
    *(short8*)&Vs[vd][32 + vk]     = vv1;
    // T14: issue next tile's loads now; they fly during this tile's compute.
    {
      int ktn = (kt + 1 < NT) ? (kt + 1) : kt;   // clamped (last iter: dummy)
      int kb64n = ktn * 64;
      kv0 = *(const short8*)(Kp + (size_t)(kb64n + krow) * PROJC + kcol);
      kv1 = *(const short8*)(Kp + (size_t)(kb64n + 32 + krow) * PROJC + kcol);
      vv0 = *(const short8*)(VTp + (size_t)vd * LSEQ + kb64n + vk);
      vv1 = *(const short8*)(VTp + (size_t)vd * LSEQ + kb64n + 32 + vk);
    }
    __syncthreads();
    for (int hf = 0; hf < 2; ++hf) {
      int kb = kb64 + hf*32;
      if (kb <= qw + 15) {
        floatx4 s0 = {0.f,0.f,0.f,0.f}, s1 = {0.f,0.f,0.f,0.f};
        __builtin_amdgcn_s_setprio(1);
        for (int s = 0; s < 4; ++s) {
          short8 kf0 = *(const short8*)&Ks[hf*32 + l16][s*32 + quad*8];
          short8 kf1 = *(const short8*)&Ks[hf*32 + 16 + l16][s*32 + quad*8];
          s0 = __builtin_amdgcn_mfma_f32_16x16x32_bf16(qf[s], kf0, s0, 0, 0, 0);
          s1 = __builtin_amdgcn_mfma_f32_16x16x32_bf16(qf[s], kf1, s1, 0, 0, 0);
        }
        __builtin_amdgcn_s_setprio(0);
        int c0 = kb + l16, c1 = kb + 16 + l16;
        for (int r = 0; r < 4; ++r) {
          int q = qw + quad*4 + r;
          float w0 = (c0 <= q) ? __expf(s0[r] * scale) : 0.f;
          float w1 = (c1 <= q) ? __expf(s1[r] * scale) : 0.f;
          lsum[r] += w0*w0 + w1*w1;
          Ps[wv][quad*4+r][l16]      = f2bf(w0);
          Ps[wv][quad*4+r][16 + l16] = f2bf(w1);
        }
        asm volatile("s_waitcnt lgkmcnt(0)" ::: "memory");
        short8 pf = *(const short8*)&Ps[wv][l16][quad*8];
        __builtin_amdgcn_s_setprio(1);
        for (int t8 = 0; t8 < 8; ++t8) {
          short8 vf = *(const short8*)&Vs[t8*16 + l16][hf*32 + quad*8];
          O[t8] = __builtin_amdgcn_mfma_f32_16x16x32_bf16(pf, vf, O[t8], 0, 0, 0);
        }
        __builtin_amdgcn_s_setprio(0);
      }
    }
  }
  for (int r = 0; r < 4; ++r) {
    float l = lsum[r];
    for (int off = 1; off < 16; off <<= 1) l += __shfl_xor(l, off);
    float inv = rsqrtf(l);
    int q = qw + quad*4 + r;
    short* orow = branch + ((size_t)(b*LSEQ + q)) * BRC + DIMD + hh*HD;
    for (int t8 = 0; t8 < 8; ++t8)
      orow[t8*16 + l16] = f2bf(O[t8][r] * inv);
  }
}

extern "C" void kernel_launch(void* const* d_in, const int* in_sizes, int n_in,
                              void* d_out, int out_size, void* d_ws, size_t ws_size,
                              hipStream_t stream) {
  const float* x     = (const float*)d_in[0];
  const float* gamma = (const float*)d_in[1];
  const float* beta  = (const float*)d_in[2];
  const float* w_qkv = (const float*)d_in[3];
  const float* w_out = (const float*)d_in[4];
  float* out = (float*)d_out;

  char* ws = (char*)d_ws;
  short* h      = (short*)ws;                                 // 16 MB
  short* proj   = (short*)(ws + (size_t)16*1024*1024);        // 80 MB (q,k slices used)
  short* branch = (short*)(ws + (size_t)96*1024*1024);        // 32 MB
  short* wq     = (short*)(ws + (size_t)128*1024*1024);       // 10 MB
  short* wo     = (short*)(ws + (size_t)138*1024*1024);       // 4 MB
  short* vt     = (short*)out;  // V^T in d_out (dead until gemm2 writes it)

  int n1 = PROJC*DIMD/4, n2 = DIMD*BRC/4;
  int nblk_cvt = (n1 + n2 + 255)/256;
  pre_kernel<<<nblk_cvt + NROWS, 256, 0, stream>>>(x, gamma, beta, h,
                                                   w_qkv, wq, n1, w_out, wo, n2,
                                                   nblk_cvt);
  gemm256<<<dim3((NROWS/256)*(PROJC/256)), 512, 0, stream>>>(h, wq, proj, vt,
                                                             branch,
                                                             NROWS, PROJC, DIMD);
  attn_kernel<<<dim3(16, BATCH*NHEAD), 512, 0, stream>>>(proj, vt, branch);
  gemm2<<<dim3(256), 512, 0, stream>>>(branch, wo, x, out, NROWS, DIMD, BRC);
}